// Round 13
// baseline (130.771 us; speedup 1.0000x reference)
//
#include <hip/hip_runtime.h>

#define DEVFN __device__ __forceinline__

typedef __attribute__((ext_vector_type(8))) short bf16x8;   // 8 bf16 = 4 VGPR
typedef __attribute__((ext_vector_type(4))) float f32x4;    // MFMA C/D

constexpr int cB = 2, cL = 2048, cD = 1024, cH = 16, cHD = 64;
constexpr int ELE  = 4194304;   // 4096*1024 (per q/k/v tensor)
constexpr int WELE = 1048576;   // 1024*1024 (per W)
constexpr int KWIN = 128;       // softmax window: kv >= 128 underflows to 0.0f
                                // even in the fp32 reference (e^-116 < e^-88)

#if __has_builtin(__builtin_amdgcn_exp2f)
#define EXP2F(x) __builtin_amdgcn_exp2f(x)
#else
#define EXP2F(x) __expf(0.6931471805599453f * (x))
#endif

DEVFN unsigned short hu(float f) {
  return (unsigned short)((__float_as_uint(f) + 0x8000u) >> 16);
}
DEVFN unsigned pkhu(float a, float b) {
  unsigned ua = __float_as_uint(a) + 0x8000u;
  unsigned ub = __float_as_uint(b) + 0x8000u;
  return __builtin_amdgcn_perm(ub, ua, 0x07060302u);  // [a_bf | b_bf<<16]
}

#if __has_builtin(__builtin_amdgcn_global_load_lds)
#define HAVE_ASYNC 1
typedef const __attribute__((address_space(1))) unsigned int* gas1_t;
typedef __attribute__((address_space(3))) unsigned int* las3_t;
#define ASYNC_CP16(g, l) \
  __builtin_amdgcn_global_load_lds((gas1_t)(g), (las3_t)(l), 16, 0, 0)
#else
#define HAVE_ASYNC 0
#endif

// XOR-swizzled ushort offset (64-ushort rows, 8 chunks of 8): conflict-free
// b128 frag reads + lane-contiguous staging (global_load_lds-compatible).
DEVFN int swzofs(int row, int cc) { return row * 64 + (((cc) ^ (row & 7)) << 3); }

// ---------------------------------------------------------------------------
// One-pass fp32 -> bf16 (byte-identical to the 128.2 µs baseline).
// q/W full; k,v only the l<128 slices per batch.
// ---------------------------------------------------------------------------
__global__ __launch_bounds__(256)
void conv_bf16(const float* __restrict__ q, const float* __restrict__ k,
               const float* __restrict__ v, const float* __restrict__ Wq,
               const float* __restrict__ Wk, const float* __restrict__ Wv,
               unsigned short* __restrict__ qb, unsigned short* __restrict__ kb,
               unsigned short* __restrict__ vb, unsigned short* __restrict__ wb) {
  const int y = blockIdx.y;
  const int i8 = (blockIdx.x * 256 + threadIdx.x) * 8;
  const float* src; unsigned short* dst; int n; size_t ofs = i8;
  switch (y) {
    case 0:  src = q;  dst = qb;          n = ELE;  break;
    case 1:  case 2: {                    // k,v: l<128 slices, b in {0,1}
      n = 2 * KWIN * cD;                  // 262144
      const size_t b = (size_t)(i8 >> 17), off = i8 & 131071;
      ofs = b * ((size_t)cL * cD) + off;
      src = (y == 1) ? k : v;  dst = (y == 1) ? kb : vb;  break;
    }
    case 3:  src = Wq; dst = wb;          n = WELE; break;
    case 4:  src = Wk; dst = wb + WELE;   n = WELE; break;
    default: src = Wv; dst = wb + 2*WELE; n = WELE; break;
  }
  if (i8 >= n) return;
  float4 a = *(const float4*)(src + ofs);
  float4 b4 = *(const float4*)(src + ofs + 4);
  uint4 o = {pkhu(a.x, a.y), pkhu(a.z, a.w), pkhu(b4.x, b4.y), pkhu(b4.z, b4.w)};
  *(uint4*)(dst + ofs) = o;
}

// ---------------------------------------------------------------------------
// Merged projections — R12: 2-phase double-buffered staging (the session's
// one measured-positive GEMM lever, R6). Tile 128(M)x64(N), BK=64, 4 waves.
// Stage tile t+1 BEFORE MFMA on tile t; ONE barrier per K-step (17 vs 32).
// LDS 48 KB (As[2] 32K + Bs[2] 16K) -> still 3 blocks/CU at 576-block grid.
// Accumulation order unchanged -> bit-identical numerics to baseline.
// bx in [0,512): Q  (A=q bf16,  B=Wq) -> Qf[bh][l][hd]
//    [512,544) : K  (A=k slices, B=Wk) -> Kc[bh][l<128][hd]
//    [544,576) : V  (A=Wv, B=v slices) -> Vc[bh][hd][l<128]
// ---------------------------------------------------------------------------
__global__ __launch_bounds__(256)
void proj_merged(const unsigned short* __restrict__ xq,
                 const unsigned short* __restrict__ xk,
                 const unsigned short* __restrict__ xv,
                 const unsigned short* __restrict__ wAll,
                 unsigned short* __restrict__ Qf,
                 unsigned short* __restrict__ Kc,
                 unsigned short* __restrict__ Vc) {
  __shared__ __align__(16) unsigned short As[2][128 * 64];  // 32 KB
  __shared__ __align__(16) unsigned short Bs[2][64 * 64];   // 16 KB
  const int tid = threadIdx.x;
  const int wv = tid >> 6, lane = tid & 63, id = lane & 15, quad = lane >> 4;
  const int wr = wv >> 1, wc = wv & 1;
  const int rl = lane >> 3, cc = (lane & 7) ^ rl;   // staging lane map

  const int bx = blockIdx.x;
  int mode, M0, N0;
  const unsigned short *A, *B;
  unsigned short* outp;
  if (bx < 512) {
    mode = 0; A = xq; B = wAll; outp = Qf;
    M0 = (bx & 31) * 128; N0 = (bx >> 5) * 64;
  } else if (bx < 544) {
    const int t = bx - 512;
    mode = 1; A = xk; B = wAll + WELE; outp = Kc;
    M0 = (t & 1) * 2048; N0 = (t >> 1) * 64;
  } else {
    const int t = bx - 544;
    mode = 2; A = wAll + 2 * WELE; B = xv; outp = Vc;
    M0 = (t & 7) * 128;
    const int y = t >> 3;
    N0 = (y >> 1) * 2048 + (y & 1) * 64;
  }

#if HAVE_ASYNC
#define STAGE_P(buf, k0)                                                       \
  {                                                                            \
    _Pragma("unroll")                                                          \
    for (int c = 0; c < 4; ++c)                                                \
      ASYNC_CP16(A + (size_t)(M0 + c * 32 + wv * 8 + rl) * cD + (k0) + cc * 8, \
                 &As[buf][(c * 32 + wv * 8) * 64]);                            \
    _Pragma("unroll")                                                          \
    for (int c = 0; c < 2; ++c)                                                \
      ASYNC_CP16(B + (size_t)(N0 + c * 32 + wv * 8 + rl) * cD + (k0) + cc * 8, \
                 &Bs[buf][(c * 32 + wv * 8) * 64]);                            \
  }
#else
#define STAGE_P(buf, k0)                                                       \
  {                                                                            \
    uint4 ra_[4], rb_[2];                                                      \
    _Pragma("unroll")                                                          \
    for (int c = 0; c < 4; ++c)                                                \
      ra_[c] = *(const uint4*)(A + (size_t)(M0 + c * 32 + wv * 8 + rl) * cD + (k0) + cc * 8); \
    _Pragma("unroll")                                                          \
    for (int c = 0; c < 2; ++c)                                                \
      rb_[c] = *(const uint4*)(B + (size_t)(N0 + c * 32 + wv * 8 + rl) * cD + (k0) + cc * 8); \
    _Pragma("unroll")                                                          \
    for (int c = 0; c < 4; ++c)                                                \
      *(uint4*)&As[buf][(c * 32 + wv * 8) * 64 + lane * 8] = ra_[c];           \
    _Pragma("unroll")                                                          \
    for (int c = 0; c < 2; ++c)                                                \
      *(uint4*)&Bs[buf][(c * 32 + wv * 8) * 64 + lane * 8] = rb_[c];           \
  }
#endif

  f32x4 acc[4][2];
#pragma unroll
  for (int i = 0; i < 4; ++i)
#pragma unroll
    for (int j = 0; j < 2; ++j) acc[i][j] = (f32x4){0.f, 0.f, 0.f, 0.f};

  STAGE_P(0, 0);
  __syncthreads();   // drain tile 0 (implicit vmcnt(0) before s_barrier)

#pragma unroll
  for (int t = 0; t < 16; ++t) {
    const int cur = t & 1;
    if (t < 15) STAGE_P(cur ^ 1, (t + 1) * 64);   // prefetch under MFMA

#pragma unroll
    for (int ks = 0; ks < 2; ++ks) {
      bf16x8 af[4], bfr[2];
#pragma unroll
      for (int mi = 0; mi < 4; ++mi)
        af[mi] = *(const bf16x8*)&As[cur][swzofs(wr * 64 + mi * 16 + id, ks * 4 + quad)];
#pragma unroll
      for (int ni = 0; ni < 2; ++ni)
        bfr[ni] = *(const bf16x8*)&Bs[cur][swzofs(wc * 32 + ni * 16 + id, ks * 4 + quad)];
#pragma unroll
      for (int mi = 0; mi < 4; ++mi)
#pragma unroll
        for (int ni = 0; ni < 2; ++ni)
          acc[mi][ni] = __builtin_amdgcn_mfma_f32_16x16x32_bf16(
              af[mi], bfr[ni], acc[mi][ni], 0, 0, 0);
    }
    __syncthreads();   // tile t+1 resident; all waves done reading buf cur
  }

  // C/D layout: col = lane&15 (N), row = quad*4 + reg (M)
#pragma unroll
  for (int mi = 0; mi < 4; ++mi) {
#pragma unroll
    for (int ni = 0; ni < 2; ++ni) {
#pragma unroll
      for (int rg = 0; rg < 4; ++rg) {
        const int mr = M0 + wr * 64 + mi * 16 + quad * 4 + rg;
        const int nc = N0 + wc * 32 + ni * 16 + id;
        size_t idx;
        if (mode == 0) {          // Qf[bh][l][hd]
          const int b = mr >> 11, l = mr & 2047, h = nc >> 6, hd = nc & 63;
          idx = ((size_t)((b * cH + h) * cL + l)) * cHD + hd;
        } else if (mode == 1) {   // Kc[bh][l<128][hd]
          const int b = mr >> 11, l = mr & 127, h = nc >> 6, hd = nc & 63;
          idx = ((size_t)((b * cH + h) * KWIN + l)) * cHD + hd;
        } else {                  // Vc[bh][hd][l<128]
          const int h = mr >> 6, hd = mr & 63, b = nc >> 11, l = nc & 127;
          idx = ((size_t)((b * cH + h) * cHD + hd)) * KWIN + l;
        }
        outp[idx] = hu(acc[mi][ni][rg]);
      }
    }
  }
}

// ---------------------------------------------------------------------------
// MFMA flash attention over kv in [0,128) (byte-identical to the 128.2 µs
// baseline). q-tile 128 (8 waves), 2 kv iterations.
// ---------------------------------------------------------------------------
__global__ __launch_bounds__(512)
void attn_mfma(const unsigned short* __restrict__ Q,
               const unsigned short* __restrict__ Kc,
               const unsigned short* __restrict__ Vc,
               float* __restrict__ out) {
  __shared__ __align__(16) unsigned short Ks[64 * 64];   // 8 KB
  __shared__ __align__(16) unsigned short Vs[64 * 64];   // 8 KB
  __shared__ __align__(16) unsigned short Ps[128 * 64];  // 16 KB
  const int tid = threadIdx.x;
  const int wv = tid >> 6, lane = tid & 63, id = lane & 15, quad = lane >> 4;
  const int bh = blockIdx.y, q0 = blockIdx.x * 128;
  const unsigned short* Qb = Q  + (size_t)bh * cL * cHD;
  const unsigned short* Kb = Kc + (size_t)bh * KWIN * cHD;
  const unsigned short* Vb = Vc + (size_t)bh * cHD * KWIN;

  constexpr float L2E = 1.4426950408889634f;
  constexpr float SC2 = 0.125f * L2E;

  bf16x8 aq[2];
#pragma unroll
  for (int ks = 0; ks < 2; ++ks)
    aq[ks] = *(const bf16x8*)(Qb + (size_t)(q0 + wv * 16 + id) * cHD + ks * 32 + quad * 8);

  f32x4 oacc[4];
#pragma unroll
  for (int i = 0; i < 4; ++i) oacc[i] = (f32x4){0.f, 0.f, 0.f, 0.f};
  float m_i[4], l_i[4];
#pragma unroll
  for (int i = 0; i < 4; ++i) { m_i[i] = -1e30f; l_i[i] = 0.f; }

  const int rl = lane >> 3, cc = (lane & 7) ^ rl;
  const int rbase = wv * 8;   // 8 waves x 8 rows = 64-row staging tile

  for (int it = 0; it < 2; ++it) {
    const int kv0 = it * 64;
#if HAVE_ASYNC
    __syncthreads();   // prior iter's Ks/Vs frag reads done
    ASYNC_CP16(Kb + (size_t)(kv0 + rbase + rl) * cHD + cc * 8, &Ks[rbase * 64]);
    ASYNC_CP16(Vb + (size_t)(rbase + rl) * KWIN + kv0 + cc * 8, &Vs[rbase * 64]);
    __syncthreads();   // vmcnt drain
#else
    uint4 kv4 = *(const uint4*)(Kb + (size_t)(kv0 + rbase + rl) * cHD + cc * 8);
    uint4 vv4 = *(const uint4*)(Vb + (size_t)(rbase + rl) * KWIN + kv0 + cc * 8);
    __syncthreads();
    *(uint4*)&Ks[rbase * 64 + lane * 8] = kv4;
    *(uint4*)&Vs[rbase * 64 + lane * 8] = vv4;
    __syncthreads();
#endif

    // S = Q K^T : wave strip [16 q][64 kv]
    f32x4 sa[4];
#pragma unroll
    for (int nt = 0; nt < 4; ++nt) sa[nt] = (f32x4){0.f, 0.f, 0.f, 0.f};
#pragma unroll
    for (int ks = 0; ks < 2; ++ks)
#pragma unroll
      for (int nt = 0; nt < 4; ++nt) {
        bf16x8 kf = *(const bf16x8*)&Ks[swzofs(nt * 16 + id, ks * 4 + quad)];
        sa[nt] = __builtin_amdgcn_mfma_f32_16x16x32_bf16(aq[ks], kf, sa[nt], 0, 0, 0);
      }

    // bias in log2 space; online softmax (row = quad*4+i, col = nt*16+id)
    const float tkv = (float)(kv0 + id) * L2E;
    float negkb[4];
#pragma unroll
    for (int nt = 0; nt < 4; ++nt) negkb[nt] = -(tkv + (float)(nt * 16) * L2E);

    float z[4][4], mt[4];
#pragma unroll
    for (int i = 0; i < 4; ++i) {
#pragma unroll
      for (int nt = 0; nt < 4; ++nt)
        z[i][nt] = fmaf(sa[nt][i], SC2, negkb[nt]);
      mt[i] = fmaxf(fmaxf(z[i][0], z[i][1]), fmaxf(z[i][2], z[i][3]));
    }
#pragma unroll
    for (int mk = 1; mk < 16; mk <<= 1)
#pragma unroll
      for (int i = 0; i < 4; ++i)
        mt[i] = fmaxf(mt[i], __shfl_xor(mt[i], mk));

    float p[4][4], rs[4], al[4];
#pragma unroll
    for (int i = 0; i < 4; ++i) {
      const float mn = fmaxf(m_i[i], mt[i]);
      al[i] = EXP2F(m_i[i] - mn);
      m_i[i] = mn;
      float s = 0.f;
#pragma unroll
      for (int nt = 0; nt < 4; ++nt) { p[i][nt] = EXP2F(z[i][nt] - mn); s += p[i][nt]; }
      rs[i] = s;
    }
#pragma unroll
    for (int mk = 1; mk < 16; mk <<= 1)
#pragma unroll
      for (int i = 0; i < 4; ++i) rs[i] += __shfl_xor(rs[i], mk);
#pragma unroll
    for (int i = 0; i < 4; ++i) l_i[i] = l_i[i] * al[i] + rs[i];
#pragma unroll
    for (int nh = 0; nh < 4; ++nh)
#pragma unroll
      for (int i = 0; i < 4; ++i) oacc[nh][i] *= al[i];

    // P (C-layout) -> bf16 -> swizzled Ps; wave-private rows => no barrier
#pragma unroll
    for (int i = 0; i < 4; ++i) {
      const int qrow = wv * 16 + quad * 4 + i;
#pragma unroll
      for (int nt = 0; nt < 4; ++nt) {
        const int col = nt * 16 + id;
        Ps[swzofs(qrow, col >> 3) + (col & 7)] = hu(p[i][nt]);
      }
    }

    // O += P V
    bf16x8 pf[2];
#pragma unroll
    for (int ks2 = 0; ks2 < 2; ++ks2)
      pf[ks2] = *(const bf16x8*)&Ps[swzofs(wv * 16 + id, ks2 * 4 + quad)];
#pragma unroll
    for (int ks2 = 0; ks2 < 2; ++ks2)
#pragma unroll
      for (int nh = 0; nh < 4; ++nh) {
        bf16x8 vf = *(const bf16x8*)&Vs[swzofs(nh * 16 + id, ks2 * 4 + quad)];
        oacc[nh] = __builtin_amdgcn_mfma_f32_16x16x32_bf16(pf[ks2], vf, oacc[nh], 0, 0, 0);
      }
  }

  // epilogue: out[b][q][h*64+hd] fp32, divide by row sum
  const int b = bh >> 4, h = bh & 15;
#pragma unroll
  for (int i = 0; i < 4; ++i) {
    const float inv = 1.0f / l_i[i];
    const int qrow = q0 + wv * 16 + quad * 4 + i;
    float* op = out + ((size_t)(b * cL + qrow)) * cD + h * cHD + id;
#pragma unroll
    for (int nh = 0; nh < 4; ++nh)
      op[nh * 16] = oacc[nh][i] * inv;
  }
}

// ---------------------------------------------------------------------------
// Buffers (d_out doubles as scratch until attn overwrites it):
//   ws:    R0 (Q proj 8.4 MB) | R1 (k slices; Kc at +1M elems) | R2 (v; Vc)
//   d_out: D0 (q bf16 8.4 MB) | D1 (W's bf16 6 MB)
// 3 launches: conv -> proj_merged (2-phase) -> attn.
// ---------------------------------------------------------------------------
extern "C" void kernel_launch(void* const* d_in, const int* in_sizes, int n_in,
                              void* d_out, int out_size, void* d_ws, size_t ws_size,
                              hipStream_t stream) {
  const float* q  = (const float*)d_in[0];
  const float* k  = (const float*)d_in[1];
  const float* v  = (const float*)d_in[2];
  const float* Wq = (const float*)d_in[3];
  const float* Wk = (const float*)d_in[4];
  const float* Wv = (const float*)d_in[5];
  float* out = (float*)d_out;

  unsigned short* R0 = (unsigned short*)d_ws;
  unsigned short* R1 = R0 + ELE;
  unsigned short* R2 = R1 + ELE;
  unsigned short* Kc = R1 + 1048576;   // 262144 elems; clear of k slice region
  unsigned short* Vc = R2 + 1048576;   // 262144 elems; clear of v slice region
  unsigned short* D0 = (unsigned short*)d_out;
  unsigned short* D1 = D0 + ELE;

  conv_bf16<<<dim3(2048, 6), dim3(256), 0, stream>>>(q, k, v, Wq, Wk, Wv,
                                                     D0, R1, R2, D1);
  proj_merged<<<dim3(576), dim3(256), 0, stream>>>(D0, R1, R2, D1,
                                                   R0, Kc, Vc);
  attn_mfma<<<dim3(16, 32), dim3(512), 0, stream>>>(R0, Kc, Vc, out);
}

// Round 14
// 128.606 us; speedup vs baseline: 1.0168x; 1.0168x over previous
//
#include <hip/hip_runtime.h>

#define DEVFN __device__ __forceinline__

typedef __attribute__((ext_vector_type(8))) short bf16x8;   // 8 bf16 = 4 VGPR
typedef __attribute__((ext_vector_type(4))) float f32x4;    // MFMA C/D

constexpr int cB = 2, cL = 2048, cD = 1024, cH = 16, cHD = 64;
constexpr int ELE  = 4194304;   // 4096*1024 (per q/k/v tensor)
constexpr int WELE = 1048576;   // 1024*1024 (per W)
constexpr int KWIN = 128;       // softmax window: kv >= 128 underflows to 0.0f
                                // even in the fp32 reference (e^-116 < e^-88)

#if __has_builtin(__builtin_amdgcn_exp2f)
#define EXP2F(x) __builtin_amdgcn_exp2f(x)
#else
#define EXP2F(x) __expf(0.6931471805599453f * (x))
#endif

DEVFN unsigned short hu(float f) {
  return (unsigned short)((__float_as_uint(f) + 0x8000u) >> 16);
}
DEVFN unsigned pkhu(float a, float b) {
  unsigned ua = __float_as_uint(a) + 0x8000u;
  unsigned ub = __float_as_uint(b) + 0x8000u;
  return __builtin_amdgcn_perm(ub, ua, 0x07060302u);  // [a_bf | b_bf<<16]
}

#if __has_builtin(__builtin_amdgcn_global_load_lds)
#define HAVE_ASYNC 1
typedef const __attribute__((address_space(1))) unsigned int* gas1_t;
typedef __attribute__((address_space(3))) unsigned int* las3_t;
#define ASYNC_CP16(g, l) \
  __builtin_amdgcn_global_load_lds((gas1_t)(g), (las3_t)(l), 16, 0, 0)
#else
#define HAVE_ASYNC 0
#endif

// XOR-swizzled ushort offset (64-ushort rows, 8 chunks of 8): conflict-free
// b128 frag reads + lane-contiguous staging (global_load_lds-compatible).
DEVFN int swzofs(int row, int cc) { return row * 64 + (((cc) ^ (row & 7)) << 3); }

// ---------------------------------------------------------------------------
// One-pass fp32 -> bf16 — R14: exact-sized 1D grid (3840 blocks, ZERO dead
// blocks; baseline launched 12288 with 8448 immediately exiting).
// Index mappings bit-identical to baseline:
//   bx [0,2048):    q full          (dst = src offset)
//   bx [2048,2304): k,v l<128 slices, STRIDED dest (= src offset) — matches
//                   proj_merged's mode-1/2 row addressing.
//   bx [2304,3840): Wq|Wk|Wv -> wb packed
// ---------------------------------------------------------------------------
__global__ __launch_bounds__(256)
void conv_bf16(const float* __restrict__ q, const float* __restrict__ k,
               const float* __restrict__ v, const float* __restrict__ Wq,
               const float* __restrict__ Wk, const float* __restrict__ Wv,
               unsigned short* __restrict__ qb, unsigned short* __restrict__ kb,
               unsigned short* __restrict__ vb, unsigned short* __restrict__ wb) {
  const int bx = blockIdx.x;
  const int t8 = threadIdx.x * 8;
  const float* src; unsigned short* dst;
  size_t sofs, dofs;
  if (bx < 2048) {                       // q full tensor
    src = q; dst = qb;
    sofs = (size_t)bx * 2048 + t8; dofs = sofs;
  } else if (bx < 2304) {                // k/v slices: 128 blocks each
    const int i = bx - 2048;
    const int is_v = i >> 7;             // 0:k 1:v
    const int j = i & 127;
    const size_t d = (size_t)j * 2048 + t8;       // [0, 262144)
    const size_t b = d >> 17;            // batch
    sofs = b * ((size_t)cL * cD) + (d & 131071);  // strided (= baseline ofs)
    dofs = sofs;                         // baseline wrote dst+ofs (sparse)
    src = is_v ? v : k; dst = is_v ? vb : kb;
  } else {                               // W's: 512 blocks each
    const int i = bx - 2304;
    const int w = i >> 9;                // 0:Wq 1:Wk 2:Wv
    const int j = i & 511;
    sofs = (size_t)j * 2048 + t8; dofs = sofs;
    src = (w == 0) ? Wq : (w == 1) ? Wk : Wv;
    dst = wb + (size_t)w * WELE;
  }
  float4 a = *(const float4*)(src + sofs);
  float4 b4 = *(const float4*)(src + sofs + 4);
  uint4 o = {pkhu(a.x, a.y), pkhu(a.z, a.w), pkhu(b4.x, b4.y), pkhu(b4.z, b4.w)};
  *(uint4*)(dst + dofs) = o;
}

// ---------------------------------------------------------------------------
// Merged projections (reverted to the 128.2 µs R12 baseline version).
// One 576-block launch. Tile 128(M)x64(N), BK=64, 4 waves. XOR-swizzled LDS;
// async staging.
// bx in [0,512): Q  (A=q bf16,  B=Wq) -> Qf[bh][l][hd]
//    [512,544) : K  (A=k slices, B=Wk) -> Kc[bh][l<128][hd]
//    [544,576) : V  (A=Wv, B=v slices) -> Vc[bh][hd][l<128]
// ---------------------------------------------------------------------------
__global__ __launch_bounds__(256)
void proj_merged(const unsigned short* __restrict__ xq,
                 const unsigned short* __restrict__ xk,
                 const unsigned short* __restrict__ xv,
                 const unsigned short* __restrict__ wAll,
                 unsigned short* __restrict__ Qf,
                 unsigned short* __restrict__ Kc,
                 unsigned short* __restrict__ Vc) {
  __shared__ __align__(16) unsigned short As[128 * 64];  // 16 KB
  __shared__ __align__(16) unsigned short Bs[64 * 64];   // 8 KB
  const int tid = threadIdx.x;
  const int wv = tid >> 6, lane = tid & 63, id = lane & 15, quad = lane >> 4;
  const int wr = wv >> 1, wc = wv & 1;
  const int rl = lane >> 3, cc = (lane & 7) ^ rl;   // staging lane map

  const int bx = blockIdx.x;
  int mode, M0, N0;
  const unsigned short *A, *B;
  unsigned short* outp;
  if (bx < 512) {
    mode = 0; A = xq; B = wAll; outp = Qf;
    M0 = (bx & 31) * 128; N0 = (bx >> 5) * 64;
  } else if (bx < 544) {
    const int t = bx - 512;
    mode = 1; A = xk; B = wAll + WELE; outp = Kc;
    M0 = (t & 1) * 2048; N0 = (t >> 1) * 64;
  } else {
    const int t = bx - 544;
    mode = 2; A = wAll + 2 * WELE; B = xv; outp = Vc;
    M0 = (t & 7) * 128;
    const int y = t >> 3;
    N0 = (y >> 1) * 2048 + (y & 1) * 64;
  }

  f32x4 acc[4][2];
#pragma unroll
  for (int i = 0; i < 4; ++i)
#pragma unroll
    for (int j = 0; j < 2; ++j) acc[i][j] = (f32x4){0.f, 0.f, 0.f, 0.f};

  for (int k0 = 0; k0 < cD; k0 += 64) {
#if HAVE_ASYNC
    __syncthreads();   // prior frag reads done before LDS overwrite
#pragma unroll
    for (int c = 0; c < 4; ++c)
      ASYNC_CP16(A + (size_t)(M0 + c * 32 + wv * 8 + rl) * cD + k0 + cc * 8,
                 &As[(c * 32 + wv * 8) * 64]);
#pragma unroll
    for (int c = 0; c < 2; ++c)
      ASYNC_CP16(B + (size_t)(N0 + c * 32 + wv * 8 + rl) * cD + k0 + cc * 8,
                 &Bs[(c * 32 + wv * 8) * 64]);
    __syncthreads();   // vmcnt drain
#else
    uint4 ra[4], rb[2];
#pragma unroll
    for (int c = 0; c < 4; ++c)
      ra[c] = *(const uint4*)(A + (size_t)(M0 + c * 32 + wv * 8 + rl) * cD + k0 + cc * 8);
#pragma unroll
    for (int c = 0; c < 2; ++c)
      rb[c] = *(const uint4*)(B + (size_t)(N0 + c * 32 + wv * 8 + rl) * cD + k0 + cc * 8);
    __syncthreads();
#pragma unroll
    for (int c = 0; c < 4; ++c) *(uint4*)&As[(c * 32 + wv * 8) * 64 + lane * 8] = ra[c];
#pragma unroll
    for (int c = 0; c < 2; ++c) *(uint4*)&Bs[(c * 32 + wv * 8) * 64 + lane * 8] = rb[c];
    __syncthreads();
#endif

#pragma unroll
    for (int ks = 0; ks < 2; ++ks) {
      bf16x8 af[4], bfr[2];
#pragma unroll
      for (int mi = 0; mi < 4; ++mi)
        af[mi] = *(const bf16x8*)&As[swzofs(wr * 64 + mi * 16 + id, ks * 4 + quad)];
#pragma unroll
      for (int ni = 0; ni < 2; ++ni)
        bfr[ni] = *(const bf16x8*)&Bs[swzofs(wc * 32 + ni * 16 + id, ks * 4 + quad)];
#pragma unroll
      for (int mi = 0; mi < 4; ++mi)
#pragma unroll
        for (int ni = 0; ni < 2; ++ni)
          acc[mi][ni] = __builtin_amdgcn_mfma_f32_16x16x32_bf16(
              af[mi], bfr[ni], acc[mi][ni], 0, 0, 0);
    }
  }

  // C/D layout: col = lane&15 (N), row = quad*4 + reg (M)
#pragma unroll
  for (int mi = 0; mi < 4; ++mi) {
#pragma unroll
    for (int ni = 0; ni < 2; ++ni) {
#pragma unroll
      for (int rg = 0; rg < 4; ++rg) {
        const int mr = M0 + wr * 64 + mi * 16 + quad * 4 + rg;
        const int nc = N0 + wc * 32 + ni * 16 + id;
        size_t idx;
        if (mode == 0) {          // Qf[bh][l][hd]
          const int b = mr >> 11, l = mr & 2047, h = nc >> 6, hd = nc & 63;
          idx = ((size_t)((b * cH + h) * cL + l)) * cHD + hd;
        } else if (mode == 1) {   // Kc[bh][l<128][hd]
          const int b = mr >> 11, l = mr & 127, h = nc >> 6, hd = nc & 63;
          idx = ((size_t)((b * cH + h) * KWIN + l)) * cHD + hd;
        } else {                  // Vc[bh][hd][l<128]
          const int h = mr >> 6, hd = mr & 63, b = nc >> 11, l = nc & 127;
          idx = ((size_t)((b * cH + h) * cHD + hd)) * KWIN + l;
        }
        outp[idx] = hu(acc[mi][ni][rg]);
      }
    }
  }
}

// ---------------------------------------------------------------------------
// MFMA flash attention over kv in [0,128) (byte-identical to the 128.2 µs
// baseline). q-tile 128 (8 waves), 2 kv iterations.
// ---------------------------------------------------------------------------
__global__ __launch_bounds__(512)
void attn_mfma(const unsigned short* __restrict__ Q,
               const unsigned short* __restrict__ Kc,
               const unsigned short* __restrict__ Vc,
               float* __restrict__ out) {
  __shared__ __align__(16) unsigned short Ks[64 * 64];   // 8 KB
  __shared__ __align__(16) unsigned short Vs[64 * 64];   // 8 KB
  __shared__ __align__(16) unsigned short Ps[128 * 64];  // 16 KB
  const int tid = threadIdx.x;
  const int wv = tid >> 6, lane = tid & 63, id = lane & 15, quad = lane >> 4;
  const int bh = blockIdx.y, q0 = blockIdx.x * 128;
  const unsigned short* Qb = Q  + (size_t)bh * cL * cHD;
  const unsigned short* Kb = Kc + (size_t)bh * KWIN * cHD;
  const unsigned short* Vb = Vc + (size_t)bh * cHD * KWIN;

  constexpr float L2E = 1.4426950408889634f;
  constexpr float SC2 = 0.125f * L2E;

  bf16x8 aq[2];
#pragma unroll
  for (int ks = 0; ks < 2; ++ks)
    aq[ks] = *(const bf16x8*)(Qb + (size_t)(q0 + wv * 16 + id) * cHD + ks * 32 + quad * 8);

  f32x4 oacc[4];
#pragma unroll
  for (int i = 0; i < 4; ++i) oacc[i] = (f32x4){0.f, 0.f, 0.f, 0.f};
  float m_i[4], l_i[4];
#pragma unroll
  for (int i = 0; i < 4; ++i) { m_i[i] = -1e30f; l_i[i] = 0.f; }

  const int rl = lane >> 3, cc = (lane & 7) ^ rl;
  const int rbase = wv * 8;   // 8 waves x 8 rows = 64-row staging tile

  for (int it = 0; it < 2; ++it) {
    const int kv0 = it * 64;
#if HAVE_ASYNC
    __syncthreads();   // prior iter's Ks/Vs frag reads done
    ASYNC_CP16(Kb + (size_t)(kv0 + rbase + rl) * cHD + cc * 8, &Ks[rbase * 64]);
    ASYNC_CP16(Vb + (size_t)(rbase + rl) * KWIN + kv0 + cc * 8, &Vs[rbase * 64]);
    __syncthreads();   // vmcnt drain
#else
    uint4 kv4 = *(const uint4*)(Kb + (size_t)(kv0 + rbase + rl) * cHD + cc * 8);
    uint4 vv4 = *(const uint4*)(Vb + (size_t)(rbase + rl) * KWIN + kv0 + cc * 8);
    __syncthreads();
    *(uint4*)&Ks[rbase * 64 + lane * 8] = kv4;
    *(uint4*)&Vs[rbase * 64 + lane * 8] = vv4;
    __syncthreads();
#endif

    // S = Q K^T : wave strip [16 q][64 kv]
    f32x4 sa[4];
#pragma unroll
    for (int nt = 0; nt < 4; ++nt) sa[nt] = (f32x4){0.f, 0.f, 0.f, 0.f};
#pragma unroll
    for (int ks = 0; ks < 2; ++ks)
#pragma unroll
      for (int nt = 0; nt < 4; ++nt) {
        bf16x8 kf = *(const bf16x8*)&Ks[swzofs(nt * 16 + id, ks * 4 + quad)];
        sa[nt] = __builtin_amdgcn_mfma_f32_16x16x32_bf16(aq[ks], kf, sa[nt], 0, 0, 0);
      }

    // bias in log2 space; online softmax (row = quad*4+i, col = nt*16+id)
    const float tkv = (float)(kv0 + id) * L2E;
    float negkb[4];
#pragma unroll
    for (int nt = 0; nt < 4; ++nt) negkb[nt] = -(tkv + (float)(nt * 16) * L2E);

    float z[4][4], mt[4];
#pragma unroll
    for (int i = 0; i < 4; ++i) {
#pragma unroll
      for (int nt = 0; nt < 4; ++nt)
        z[i][nt] = fmaf(sa[nt][i], SC2, negkb[nt]);
      mt[i] = fmaxf(fmaxf(z[i][0], z[i][1]), fmaxf(z[i][2], z[i][3]));
    }
#pragma unroll
    for (int mk = 1; mk < 16; mk <<= 1)
#pragma unroll
      for (int i = 0; i < 4; ++i)
        mt[i] = fmaxf(mt[i], __shfl_xor(mt[i], mk));

    float p[4][4], rs[4], al[4];
#pragma unroll
    for (int i = 0; i < 4; ++i) {
      const float mn = fmaxf(m_i[i], mt[i]);
      al[i] = EXP2F(m_i[i] - mn);
      m_i[i] = mn;
      float s = 0.f;
#pragma unroll
      for (int nt = 0; nt < 4; ++nt) { p[i][nt] = EXP2F(z[i][nt] - mn); s += p[i][nt]; }
      rs[i] = s;
    }
#pragma unroll
    for (int mk = 1; mk < 16; mk <<= 1)
#pragma unroll
      for (int i = 0; i < 4; ++i) rs[i] += __shfl_xor(rs[i], mk);
#pragma unroll
    for (int i = 0; i < 4; ++i) l_i[i] = l_i[i] * al[i] + rs[i];
#pragma unroll
    for (int nh = 0; nh < 4; ++nh)
#pragma unroll
      for (int i = 0; i < 4; ++i) oacc[nh][i] *= al[i];

    // P (C-layout) -> bf16 -> swizzled Ps; wave-private rows => no barrier
#pragma unroll
    for (int i = 0; i < 4; ++i) {
      const int qrow = wv * 16 + quad * 4 + i;
#pragma unroll
      for (int nt = 0; nt < 4; ++nt) {
        const int col = nt * 16 + id;
        Ps[swzofs(qrow, col >> 3) + (col & 7)] = hu(p[i][nt]);
      }
    }

    // O += P V
    bf16x8 pf[2];
#pragma unroll
    for (int ks2 = 0; ks2 < 2; ++ks2)
      pf[ks2] = *(const bf16x8*)&Ps[swzofs(wv * 16 + id, ks2 * 4 + quad)];
#pragma unroll
    for (int ks2 = 0; ks2 < 2; ++ks2)
#pragma unroll
      for (int nh = 0; nh < 4; ++nh) {
        bf16x8 vf = *(const bf16x8*)&Vs[swzofs(nh * 16 + id, ks2 * 4 + quad)];
        oacc[nh] = __builtin_amdgcn_mfma_f32_16x16x32_bf16(pf[ks2], vf, oacc[nh], 0, 0, 0);
      }
  }

  // epilogue: out[b][q][h*64+hd] fp32, divide by row sum
  const int b = bh >> 4, h = bh & 15;
#pragma unroll
  for (int i = 0; i < 4; ++i) {
    const float inv = 1.0f / l_i[i];
    const int qrow = q0 + wv * 16 + quad * 4 + i;
    float* op = out + ((size_t)(b * cL + qrow)) * cD + h * cHD + id;
#pragma unroll
    for (int nh = 0; nh < 4; ++nh)
      op[nh * 16] = oacc[nh][i] * inv;
  }
}

// ---------------------------------------------------------------------------
// Buffers (d_out doubles as scratch until attn overwrites it):
//   ws:    R0 (Q proj 8.4 MB) | R1 (k slices sparse; Kc at +1M elems) | R2 (v; Vc)
//   d_out: D0 (q bf16 8.4 MB) | D1 (W's bf16 6 MB)
// 3 launches: conv (3840 blocks, exact) -> proj_merged -> attn.
// ---------------------------------------------------------------------------
extern "C" void kernel_launch(void* const* d_in, const int* in_sizes, int n_in,
                              void* d_out, int out_size, void* d_ws, size_t ws_size,
                              hipStream_t stream) {
  const float* q  = (const float*)d_in[0];
  const float* k  = (const float*)d_in[1];
  const float* v  = (const float*)d_in[2];
  const float* Wq = (const float*)d_in[3];
  const float* Wk = (const float*)d_in[4];
  const float* Wv = (const float*)d_in[5];
  float* out = (float*)d_out;

  unsigned short* R0 = (unsigned short*)d_ws;
  unsigned short* R1 = R0 + ELE;
  unsigned short* R2 = R1 + ELE;
  unsigned short* Kc = R1 + 1048576;   // 262144 elems; clear of k slice region
  unsigned short* Vc = R2 + 1048576;   // 262144 elems; clear of v slice region
  unsigned short* D0 = (unsigned short*)d_out;
  unsigned short* D1 = D0 + ELE;

  conv_bf16<<<dim3(3840), dim3(256), 0, stream>>>(q, k, v, Wq, Wk, Wv,
                                                  D0, R1, R2, D1);
  proj_merged<<<dim3(576), dim3(256), 0, stream>>>(D0, R1, R2, D1,
                                                   R0, Kc, Vc);
  attn_mfma<<<dim3(16, 32), dim3(512), 0, stream>>>(R0, Kc, Vc, out);
}